// Round 5
// baseline (1223.485 us; speedup 1.0000x reference)
//
#include <hip/hip_runtime.h>
#include <hip/hip_bf16.h>

#define NT    10
#define NN    2048   // n_neurons
#define CA3C  2048
#define SEQ   1024
#define SPARS 0.05f
#define LRC   0.01f

typedef float    f32x4 __attribute__((ext_vector_type(4)));
typedef unsigned u32x4 __attribute__((ext_vector_type(4)));

// ---------------- Phase A: hippo_input[s][n] = sum_t tok_spike*(1+0.5*pos_spike) ----
__global__ __launch_bounds__(256) void k_hippo(const int* __restrict__ tok,
        const float* __restrict__ sdr, const float* __restrict__ pos,
        float* __restrict__ hippo) {
    int s = blockIdx.x;
    int n = (blockIdx.y * 256 + threadIdx.x) * 4;
    const float* sp = sdr + (long)tok[s] * (NT * NN) + n;
    const float* pp = pos + (long)s * (NT * NN) + n;
    float a0 = 0.f, a1 = 0.f, a2 = 0.f, a3 = 0.f;
    #pragma unroll
    for (int t = 0; t < NT; ++t) {
        float4 sv = *(const float4*)(sp + t * NN);
        float4 pv = *(const float4*)(pp + t * NN);
        if (sv.x < SPARS) a0 += (pv.x < SPARS) ? 1.5f : 1.0f;
        if (sv.y < SPARS) a1 += (pv.y < SPARS) ? 1.5f : 1.0f;
        if (sv.z < SPARS) a2 += (pv.z < SPARS) ? 1.5f : 1.0f;
        if (sv.w < SPARS) a3 += (pv.w < SPARS) ? 1.5f : 1.0f;
    }
    *(float4*)(hippo + (long)s * NN + n) = make_float4(a0, a1, a2, a3);
}

// ---------------- Phase B: dots[s][c] = hippo[s] . w_hippo[c]  (fp32 tiled GEMM) ----
__global__ __launch_bounds__(256) void k_gemm(const float* __restrict__ A,
        const float* __restrict__ B, float* __restrict__ C) {
    __shared__ float As[32][68];   // [k][m], padded row stride 68 (16B aligned)
    __shared__ float Bs[32][68];   // [k][n]
    int tid = threadIdx.x;
    int tx = tid & 15, ty = tid >> 4;
    int m0 = blockIdx.y * 64, n0 = blockIdx.x * 64;
    int lr = tid >> 3;            // 0..31
    int lk = (tid & 7) * 4;       // 0..28
    float acc[4][4] = {};
    for (int k0 = 0; k0 < NN; k0 += 32) {
        float4 a0 = *(const float4*)(A + (m0 + lr) * NN + k0 + lk);
        float4 a1 = *(const float4*)(A + (m0 + lr + 32) * NN + k0 + lk);
        float4 b0 = *(const float4*)(B + (n0 + lr) * NN + k0 + lk);
        float4 b1 = *(const float4*)(B + (n0 + lr + 32) * NN + k0 + lk);
        __syncthreads();
        As[lk + 0][lr] = a0.x; As[lk + 1][lr] = a0.y; As[lk + 2][lr] = a0.z; As[lk + 3][lr] = a0.w;
        As[lk + 0][lr + 32] = a1.x; As[lk + 1][lr + 32] = a1.y; As[lk + 2][lr + 32] = a1.z; As[lk + 3][lr + 32] = a1.w;
        Bs[lk + 0][lr] = b0.x; Bs[lk + 1][lr] = b0.y; Bs[lk + 2][lr] = b0.z; Bs[lk + 3][lr] = b0.w;
        Bs[lk + 0][lr + 32] = b1.x; Bs[lk + 1][lr + 32] = b1.y; Bs[lk + 2][lr + 32] = b1.z; Bs[lk + 3][lr + 32] = b1.w;
        __syncthreads();
        #pragma unroll
        for (int k = 0; k < 32; ++k) {
            float4 av = *(const float4*)&As[k][ty * 4];
            float4 bv = *(const float4*)&Bs[k][tx * 4];
            float aa[4] = {av.x, av.y, av.z, av.w};
            float bb[4] = {bv.x, bv.y, bv.z, bv.w};
            #pragma unroll
            for (int i = 0; i < 4; ++i)
                #pragma unroll
                for (int j = 0; j < 4; ++j)
                    acc[i][j] = fmaf(aa[i], bb[j], acc[i][j]);
        }
    }
    #pragma unroll
    for (int i = 0; i < 4; ++i)
        *(float4*)(C + (long)(m0 + ty * 4 + i) * CA3C + n0 + tx * 4) =
            make_float4(acc[i][0], acc[i][1], acc[i][2], acc[i][3]);
}

// ---------------- Phase B2: fp64 re-check of near-zero dots (sign safety) ----------
__global__ __launch_bounds__(256) void k_fixup(const float* __restrict__ hippo,
        const float* __restrict__ w, float* __restrict__ dots) {
    long i = (long)blockIdx.x * 256 + threadIdx.x;
    float d = dots[i];
    if (fabsf(d) < 1e-3f) {
        int s = (int)(i / CA3C), c = (int)(i % CA3C);
        const float* hr = hippo + (long)s * NN;
        const float* wr = w + (long)c * NN;
        double acc = 0.0;
        for (int n = 0; n < NN; ++n) acc += (double)hr[n] * (double)wr[n];
        dots[i] = (acc > 0.0) ? 1.0f : -1.0f;   // only the sign is consumed
    }
}

// ---------------- Phase C0: pack pre bits TRANSPOSED preT[w][1024] + popcounts -----
__global__ __launch_bounds__(64) void k_packpre(const float* __restrict__ dots,
        unsigned* __restrict__ preT, float* __restrict__ popf) {
    int s = blockIdx.x;                        // 0..1023 (step index)
    int w = threadIdx.x;                       // 0..63 -> word index
    const float* row = dots + (long)s * CA3C + w * 32;
    unsigned m = 0;
    #pragma unroll
    for (int j = 0; j < 32; ++j) m |= (row[j] > 0.0f ? 1u : 0u) << j;
    preT[w * SEQ + s] = m;                     // transposed: 4 consecutive steps -> uint4
    int pc = __popc(m);
    #pragma unroll
    for (int o = 1; o < 64; o <<= 1) pc += __shfl_xor(pc, o, 64);
    if (w == 0) popf[s] = (float)pc;
}

// ---------------- Phase C1: pack post bits transposed [r][32 words over steps] -----
__global__ __launch_bounds__(256) void k_packpost(const float* __restrict__ dots,
        unsigned* __restrict__ postT) {
    int r = blockIdx.x * 256 + threadIdx.x;    // 0..2047
    #pragma unroll 1
    for (int wi = 0; wi < 32; ++wi) {
        unsigned m = 0;
        int jmax = (wi == 31) ? 31 : 32;       // steps s = wi*32+j, s <= 1022
        for (int j = 0; j < jmax; ++j) {
            int s = wi * 32 + j;
            m |= (dots[(long)(s + 1) * CA3C + r] > 0.0f ? 1u : 0u) << j;
        }
        postT[r * 32 + wi] = m;
    }
}

// ---------------- DPP-based full-wave (64 lane) sum; result broadcast via lane 63 ---
__device__ __forceinline__ float wave_sum64(float x) {
    #define DPPADD(ctrl, rmask) \
        x += __int_as_float(__builtin_amdgcn_update_dpp(0, __float_as_int(x), ctrl, rmask, 0xF, true))
    DPPADD(0xB1, 0xF);    // quad_perm [1,0,3,2]  (xor 1)
    DPPADD(0x4E, 0xF);    // quad_perm [2,3,0,1]  (xor 2)
    DPPADD(0x141, 0xF);   // row_half_mirror      (xor 4)
    DPPADD(0x140, 0xF);   // row_mirror           (xor 8)
    DPPADD(0x142, 0xA);   // row_bcast15 -> rows 1,3
    DPPADD(0x143, 0xC);   // row_bcast31 -> rows 2,3
    #undef DPPADD
    return __int_as_float(__builtin_amdgcn_readlane(__float_as_int(x), 63));
}

// ---------------- Phase D: per-row sequential Hebbian scan (1 wave = 1 row) --------
// V held in 32 NAMED SCALAR floats (no arrays, no vector tuples -> no aligned-quad
// register pressure; R1-R4 all ended with V in scratch => L2-BW-bound at ~31 TB/s).
// KEEPALIVE: empty asm with "+v" on all 32 scalars once per 4-step group forces
// VGPR residency. 1 wave per block; explicit amdgpu attrs give the allocator a
// 512-VGPR budget.
#define VLIST V00,V01,V02,V03,V04,V05,V06,V07,V08,V09,V10,V11,V12,V13,V14,V15, \
              V16,V17,V18,V19,V20,V21,V22,V23,V24,V25,V26,V27,V28,V29,V30,V31

#define HEB_E(J, VV, DD) { \
    float f = (float)((m >> (J)) & 1u); \
    DD = fmaf(f, VV, DD); \
    VV = fmaf(f, c, VV); }

#define HEB_STEP(B, POPB) { \
    if ((pw >> (((sg & 7) << 2) + B)) & 1u) { \
        unsigned m = mg[B]; \
        float c = LRC * inv_alpha; \
        float d0 = 0.f, d1 = 0.f, d2 = 0.f, d3 = 0.f; \
        HEB_E( 0, V00, d0) HEB_E( 1, V01, d1) HEB_E( 2, V02, d2) HEB_E( 3, V03, d3) \
        HEB_E( 4, V04, d0) HEB_E( 5, V05, d1) HEB_E( 6, V06, d2) HEB_E( 7, V07, d3) \
        HEB_E( 8, V08, d0) HEB_E( 9, V09, d1) HEB_E(10, V10, d2) HEB_E(11, V11, d3) \
        HEB_E(12, V12, d0) HEB_E(13, V13, d1) HEB_E(14, V14, d2) HEB_E(15, V15, d3) \
        HEB_E(16, V16, d0) HEB_E(17, V17, d1) HEB_E(18, V18, d2) HEB_E(19, V19, d3) \
        HEB_E(20, V20, d0) HEB_E(21, V21, d1) HEB_E(22, V22, d2) HEB_E(23, V23, d3) \
        HEB_E(24, V24, d0) HEB_E(25, V25, d1) HEB_E(26, V26, d2) HEB_E(27, V27, d3) \
        HEB_E(28, V28, d0) HEB_E(29, V29, d1) HEB_E(30, V30, d2) HEB_E(31, V31, d3) \
        float dot = wave_sum64((d0 + d1) + (d2 + d3)); \
        nu = fmaf(2.f * LRC, alpha * dot, fmaf(LRC * LRC, POPB, nu)); \
        float t = fmaxf(nu, 1.f); \
        alpha *= rsqrtf(t); inv_alpha *= sqrtf(t); nu = fminf(nu, 1.f); \
        if (alpha < 1e-6f) { \
            V00 *= alpha; V01 *= alpha; V02 *= alpha; V03 *= alpha; \
            V04 *= alpha; V05 *= alpha; V06 *= alpha; V07 *= alpha; \
            V08 *= alpha; V09 *= alpha; V10 *= alpha; V11 *= alpha; \
            V12 *= alpha; V13 *= alpha; V14 *= alpha; V15 *= alpha; \
            V16 *= alpha; V17 *= alpha; V18 *= alpha; V19 *= alpha; \
            V20 *= alpha; V21 *= alpha; V22 *= alpha; V23 *= alpha; \
            V24 *= alpha; V25 *= alpha; V26 *= alpha; V27 *= alpha; \
            V28 *= alpha; V29 *= alpha; V30 *= alpha; V31 *= alpha; \
            alpha = 1.f; inv_alpha = 1.f; \
        } \
    } }

__global__ __attribute__((amdgpu_flat_work_group_size(64, 64), amdgpu_waves_per_eu(1, 4)))
void k_scan(const float* __restrict__ W0,
        const unsigned* __restrict__ preT, const float* __restrict__ popf,
        const unsigned* __restrict__ postT, float* __restrict__ Wout) {
    int r = blockIdx.x;                              // 1 wave per block = 1 row
    int lane = threadIdx.x;                          // 0..63
    const float* src = W0 + (long)r * CA3C + lane * 32;
    f32x4 L0 = *(const f32x4*)(src +  0), L1 = *(const f32x4*)(src +  4);
    f32x4 L2 = *(const f32x4*)(src +  8), L3 = *(const f32x4*)(src + 12);
    f32x4 L4 = *(const f32x4*)(src + 16), L5 = *(const f32x4*)(src + 20);
    f32x4 L6 = *(const f32x4*)(src + 24), L7 = *(const f32x4*)(src + 28);
    float V00=L0.x,V01=L0.y,V02=L0.z,V03=L0.w, V04=L1.x,V05=L1.y,V06=L1.z,V07=L1.w;
    float V08=L2.x,V09=L2.y,V10=L2.z,V11=L2.w, V12=L3.x,V13=L3.y,V14=L3.z,V15=L3.w;
    float V16=L4.x,V17=L4.y,V18=L4.z,V19=L4.w, V20=L5.x,V21=L5.y,V22=L5.z,V23=L5.w;
    float V24=L6.x,V25=L6.y,V26=L6.z,V27=L6.w, V28=L7.x,V29=L7.y,V30=L7.z,V31=L7.w;

    float p0 = 0.f, p1 = 0.f, p2 = 0.f, p3 = 0.f;
    p0=fmaf(V00,V00,p0); p1=fmaf(V01,V01,p1); p2=fmaf(V02,V02,p2); p3=fmaf(V03,V03,p3);
    p0=fmaf(V04,V04,p0); p1=fmaf(V05,V05,p1); p2=fmaf(V06,V06,p2); p3=fmaf(V07,V07,p3);
    p0=fmaf(V08,V08,p0); p1=fmaf(V09,V09,p1); p2=fmaf(V10,V10,p2); p3=fmaf(V11,V11,p3);
    p0=fmaf(V12,V12,p0); p1=fmaf(V13,V13,p1); p2=fmaf(V14,V14,p2); p3=fmaf(V15,V15,p3);
    p0=fmaf(V16,V16,p0); p1=fmaf(V17,V17,p1); p2=fmaf(V18,V18,p2); p3=fmaf(V19,V19,p3);
    p0=fmaf(V20,V20,p0); p1=fmaf(V21,V21,p1); p2=fmaf(V22,V22,p2); p3=fmaf(V23,V23,p3);
    p0=fmaf(V24,V24,p0); p1=fmaf(V25,V25,p1); p2=fmaf(V26,V26,p2); p3=fmaf(V27,V27,p3);
    p0=fmaf(V28,V28,p0); p1=fmaf(V29,V29,p1); p2=fmaf(V30,V30,p2); p3=fmaf(V31,V31,p3);
    float nu = wave_sum64((p0 + p1) + (p2 + p3));
    float alpha = 1.f, inv_alpha = 1.f;
    {
        float t = fmaxf(nu, 1.f);
        alpha *= rsqrtf(t); inv_alpha *= sqrtf(t); nu = fminf(nu, 1.f);
    }

    const u32x4* pT4 = (const u32x4*)(preT + (long)lane * SEQ);  // 4 steps per load
    const f32x4* pF4 = (const f32x4*)popf;
    u32x4 mg_n  = pT4[0];
    f32x4 pop_n = pF4[0];
    unsigned pw = 0;
    #pragma unroll 1
    for (int sg = 0; sg < SEQ / 4; ++sg) {           // 256 groups x 4 steps
        asm volatile("" : "+v"(V00),"+v"(V01),"+v"(V02),"+v"(V03),"+v"(V04),"+v"(V05),
                          "+v"(V06),"+v"(V07),"+v"(V08),"+v"(V09),"+v"(V10),"+v"(V11),
                          "+v"(V12),"+v"(V13),"+v"(V14),"+v"(V15),"+v"(V16),"+v"(V17),
                          "+v"(V18),"+v"(V19),"+v"(V20),"+v"(V21),"+v"(V22),"+v"(V23),
                          "+v"(V24),"+v"(V25),"+v"(V26),"+v"(V27),"+v"(V28),"+v"(V29),
                          "+v"(V30),"+v"(V31));
        u32x4 mg   = mg_n;
        f32x4 popg = pop_n;
        if (sg + 1 < SEQ / 4) { mg_n = pT4[sg + 1]; pop_n = pF4[sg + 1]; }
        if ((sg & 7) == 0) pw = __builtin_amdgcn_readfirstlane(postT[r * 32 + (sg >> 3)]);
        HEB_STEP(0, popg.x) HEB_STEP(1, popg.y) HEB_STEP(2, popg.z) HEB_STEP(3, popg.w)
        // step 1023 (sg=255,B=3) is always inactive: postT word 31 bit 31 == 0
    }
    float* dst = Wout + (long)r * CA3C + lane * 32;
    f32x4 S0 = {V00*alpha, V01*alpha, V02*alpha, V03*alpha};
    f32x4 S1 = {V04*alpha, V05*alpha, V06*alpha, V07*alpha};
    f32x4 S2 = {V08*alpha, V09*alpha, V10*alpha, V11*alpha};
    f32x4 S3 = {V12*alpha, V13*alpha, V14*alpha, V15*alpha};
    f32x4 S4 = {V16*alpha, V17*alpha, V18*alpha, V19*alpha};
    f32x4 S5 = {V20*alpha, V21*alpha, V22*alpha, V23*alpha};
    f32x4 S6 = {V24*alpha, V25*alpha, V26*alpha, V27*alpha};
    f32x4 S7 = {V28*alpha, V29*alpha, V30*alpha, V31*alpha};
    *(f32x4*)(dst +  0) = S0; *(f32x4*)(dst +  4) = S1;
    *(f32x4*)(dst +  8) = S2; *(f32x4*)(dst + 12) = S3;
    *(f32x4*)(dst + 16) = S4; *(f32x4*)(dst + 20) = S5;
    *(f32x4*)(dst + 24) = S6; *(f32x4*)(dst + 28) = S7;
}

extern "C" void kernel_launch(void* const* d_in, const int* in_sizes, int n_in,
                              void* d_out, int out_size, void* d_ws, size_t ws_size,
                              hipStream_t stream) {
    const int*   tok     = (const int*)d_in[0];
    const float* sdr     = (const float*)d_in[1];
    const float* pos     = (const float*)d_in[2];
    const float* w_hippo = (const float*)d_in[3];
    const float* assoc   = (const float*)d_in[4];
    float* out = (float*)d_out;

    char* ws = (char*)d_ws;
    float*    hippo = (float*)(ws);                        // 8 MB
    float*    dots  = (float*)(ws + 8388608);              // 8 MB
    unsigned* preT  = (unsigned*)(ws + 16777216);          // 256 KB (transposed bits)
    unsigned* postT = (unsigned*)(ws + 17039360);          // 256 KB
    float*    popf  = (float*)(ws + 17301504);             // 4 KB

    k_hippo   <<<dim3(SEQ, 2),            256, 0, stream>>>(tok, sdr, pos, hippo);
    k_gemm    <<<dim3(CA3C/64, SEQ/64),   256, 0, stream>>>(hippo, w_hippo, dots);
    k_fixup   <<<dim3((SEQ*CA3C)/256),    256, 0, stream>>>(hippo, w_hippo, dots);
    k_packpre <<<dim3(SEQ),                64, 0, stream>>>(dots, preT, popf);
    k_packpost<<<dim3(CA3C/256),          256, 0, stream>>>(dots, postT);
    k_scan    <<<dim3(CA3C),               64, 0, stream>>>(assoc, preT, popf, postT, out);
}